// Round 4
// baseline (829.402 us; speedup 1.0000x reference)
//
#include <hip/hip_runtime.h>
#include <math.h>

typedef __bf16 bf16_t;
typedef __bf16 v8bf __attribute__((ext_vector_type(8)));
typedef float  v4f  __attribute__((ext_vector_type(4)));

// ---------------------------------------------------------------------------
// Kernel 1: QKV = h @ [wq|wk|wv]^T with fused RoPE on Q,K.
// A (h) and W are fp32 in global; converted to bf16 during LDS staging.
// Output per tensor: [B*H=32][T=2048][64] bf16.
// ---------------------------------------------------------------------------
__global__ __launch_bounds__(256) void qkv_gemm_rope(
    const float* __restrict__ A,    // h [4096][1024] fp32
    const float* __restrict__ wq,
    const float* __restrict__ wk,
    const float* __restrict__ wv,
    bf16_t* __restrict__ qo, bf16_t* __restrict__ ko, bf16_t* __restrict__ vo)
{
    __shared__ __align__(16) bf16_t As[128 * 32];
    __shared__ __align__(16) bf16_t Bs[128 * 32];

    const int tid = threadIdx.x;
    const int n0  = blockIdx.x * 128;       // 0..2944 (fused QKV columns)
    const int m0  = blockIdx.y * 128;
    const int sel = n0 >> 10;               // 0=Q 1=K 2=V
    const float* W = (sel == 0) ? wq : (sel == 1) ? wk : wv;
    const int wr0 = n0 & 1023;

    const int wave = tid >> 6;
    const int lane = tid & 63;
    const int wrow = (wave >> 1) * 64;
    const int wcol = (wave & 1) * 64;
    const int l16  = lane & 15;
    const int quad = lane >> 4;

    v4f acc[4][4];
    #pragma unroll
    for (int i = 0; i < 4; ++i)
        #pragma unroll
        for (int j = 0; j < 4; ++j) acc[i][j] = (v4f)(0.0f);

    for (int kt = 0; kt < 32; ++kt) {
        const int k0 = kt * 32;
        #pragma unroll
        for (int rep = 0; rep < 2; ++rep) {
            const int c   = rep * 256 + tid;     // chunk 0..511
            const int row = c >> 2;              // 0..127
            const int col = (c & 3) * 8;         // 0,8,16,24
            const float* pa = A + (size_t)(m0 + row) * 1024 + k0 + col;
            const float* pb = W + (size_t)(wr0 + row) * 1024 + k0 + col;
            const float4 a0 = *(const float4*)pa;
            const float4 a1 = *(const float4*)(pa + 4);
            const float4 b0 = *(const float4*)pb;
            const float4 b1 = *(const float4*)(pb + 4);
            v8bf av, bv;
            av[0] = (bf16_t)a0.x; av[1] = (bf16_t)a0.y; av[2] = (bf16_t)a0.z; av[3] = (bf16_t)a0.w;
            av[4] = (bf16_t)a1.x; av[5] = (bf16_t)a1.y; av[6] = (bf16_t)a1.z; av[7] = (bf16_t)a1.w;
            bv[0] = (bf16_t)b0.x; bv[1] = (bf16_t)b0.y; bv[2] = (bf16_t)b0.z; bv[3] = (bf16_t)b0.w;
            bv[4] = (bf16_t)b1.x; bv[5] = (bf16_t)b1.y; bv[6] = (bf16_t)b1.z; bv[7] = (bf16_t)b1.w;
            *(v8bf*)&As[c * 8] = av;
            *(v8bf*)&Bs[c * 8] = bv;
        }
        __syncthreads();

        v8bf af[4], bfb[4];
        #pragma unroll
        for (int i = 0; i < 4; ++i) {
            af[i]  = *(const v8bf*)&As[(wrow + i * 16 + l16) * 32 + quad * 8];
            bfb[i] = *(const v8bf*)&Bs[(wcol + i * 16 + l16) * 32 + quad * 8];
        }
        #pragma unroll
        for (int i = 0; i < 4; ++i)
            #pragma unroll
            for (int j = 0; j < 4; ++j)
                acc[i][j] = __builtin_amdgcn_mfma_f32_16x16x32_bf16(
                    af[i], bfb[j], acc[i][j], 0, 0, 0);
        __syncthreads();
    }

    bf16_t* OUT = (sel == 0) ? qo : (sel == 1) ? ko : vo;
    #pragma unroll
    for (int i = 0; i < 4; ++i) {
        #pragma unroll
        for (int j = 0; j < 4; ++j) {
            #pragma unroll
            for (int r = 0; r < 4; ++r) {
                const int row = wrow + i * 16 + quad * 4 + r;  // C/D: row=quad*4+reg
                const int col = wcol + j * 16 + l16;           //      col=lane&15
                const int m = m0 + row;
                const int n = n0 + col;
                float v = acc[i][j][r];
                const float vp = __shfl_xor(v, 1);  // RoPE partner: col n^1 = lane^1
                const int t = m & 2047;
                const int d = n & 63;
                if (sel < 2) {
                    const int kk = d >> 1;
                    const float freq = exp2f((float)kk * -0.4152410118609203f); // 10000^(-kk/32)
                    const float ang  = (float)t * freq;
                    float sn, cs;
                    sincosf(ang, &sn, &cs);
                    v = ((d & 1) == 0) ? (cs * v - sn * vp) : (sn * vp + cs * v);
                }
                const int b  = m >> 11;
                const int hd = (n >> 6) & 15;
                OUT[(((size_t)(b * 16 + hd) * 2048) + t) * 64 + d] = (bf16_t)v;
            }
        }
    }
}

// ---------------------------------------------------------------------------
// Kernel 2: causal flash attention, scalar fp32 math, softmax state in
// registers (identical across each 16-lane row group via butterfly shuffles).
// Q,K,V: [32][2048][64] bf16. Output og: [4096][1024] bf16.
// ---------------------------------------------------------------------------
__global__ __launch_bounds__(256) void attn_kernel(
    const bf16_t* __restrict__ qg,
    const bf16_t* __restrict__ kg,
    const bf16_t* __restrict__ vg,
    bf16_t* __restrict__ og)
{
    __shared__ float  Qs[64 * 65];
    __shared__ float  Ks[64 * 65];
    __shared__ float  Vs[64 * 65];
    __shared__ bf16_t Sp[64 * 66];

    const int tid = threadIdx.x;
    const int qt  = blockIdx.x;    // 0..31
    const int bh  = blockIdx.y;    // 0..31
    const int rb  = tid >> 4;      // row block 0..15
    const int cb  = tid & 15;      // col block 0..15

    const bf16_t* qbase = qg + (((size_t)bh * 2048) + (size_t)qt * 64) * 64;
    #pragma unroll
    for (int rep = 0; rep < 2; ++rep) {
        const int c = rep * 256 + tid;
        const int row = c >> 3, col8 = (c & 7) * 8;
        v8bf v = *(const v8bf*)(qbase + row * 64 + col8);
        #pragma unroll
        for (int e = 0; e < 8; ++e) Qs[row * 65 + col8 + e] = (float)v[e];
    }

    float m_r[4], l_r[4];
    float o_reg[4][4];
    #pragma unroll
    for (int i = 0; i < 4; ++i) {
        m_r[i] = -1e30f; l_r[i] = 0.0f;
        #pragma unroll
        for (int j = 0; j < 4; ++j) o_reg[i][j] = 0.0f;
    }
    __syncthreads();

    for (int kt = 0; kt <= qt; ++kt) {
        const bf16_t* kbase = kg + (((size_t)bh * 2048) + (size_t)kt * 64) * 64;
        const bf16_t* vbase = vg + (((size_t)bh * 2048) + (size_t)kt * 64) * 64;
        #pragma unroll
        for (int rep = 0; rep < 2; ++rep) {
            const int c = rep * 256 + tid;
            const int row = c >> 3, col8 = (c & 7) * 8;
            v8bf kv = *(const v8bf*)(kbase + row * 64 + col8);
            v8bf vv = *(const v8bf*)(vbase + row * 64 + col8);
            #pragma unroll
            for (int e = 0; e < 8; ++e) {
                Ks[row * 65 + col8 + e] = (float)kv[e];
                Vs[row * 65 + col8 + e] = (float)vv[e];
            }
        }
        __syncthreads();

        // ---- scores S = Q K^T / 8 over the 64x64 tile ----
        float sc[4][4];
        #pragma unroll
        for (int i = 0; i < 4; ++i)
            #pragma unroll
            for (int j = 0; j < 4; ++j) sc[i][j] = 0.0f;
        #pragma unroll 4
        for (int d = 0; d < 64; ++d) {
            float qv[4], kv[4];
            #pragma unroll
            for (int i = 0; i < 4; ++i) qv[i] = Qs[(rb * 4 + i) * 65 + d];
            #pragma unroll
            for (int j = 0; j < 4; ++j) kv[j] = Ks[(cb * 4 + j) * 65 + d];
            #pragma unroll
            for (int i = 0; i < 4; ++i)
                #pragma unroll
                for (int j = 0; j < 4; ++j)
                    sc[i][j] = fmaf(qv[i], kv[j], sc[i][j]);
        }
        const bool diag = (kt == qt);
        #pragma unroll
        for (int i = 0; i < 4; ++i) {
            const int q_idx = qt * 64 + rb * 4 + i;
            #pragma unroll
            for (int j = 0; j < 4; ++j) {
                float s = sc[i][j] * 0.125f;
                if (diag && (kt * 64 + cb * 4 + j > q_idx)) s = -1e30f;
                sc[i][j] = s;
            }
        }

        // ---- online softmax, all state in registers ----
        float alpha_r[4];
        #pragma unroll
        for (int i = 0; i < 4; ++i) {
            const int row = rb * 4 + i;
            float pm = fmaxf(fmaxf(sc[i][0], sc[i][1]), fmaxf(sc[i][2], sc[i][3]));
            #pragma unroll
            for (int msk = 1; msk < 16; msk <<= 1) pm = fmaxf(pm, __shfl_xor(pm, msk));
            const float m_new = fmaxf(m_r[i], pm);
            float ps = 0.0f;
            #pragma unroll
            for (int j = 0; j < 4; ++j) {
                const float p = __expf(sc[i][j] - m_new);
                sc[i][j] = p;
                ps += p;
            }
            #pragma unroll
            for (int msk = 1; msk < 16; msk <<= 1) ps += __shfl_xor(ps, msk);
            alpha_r[i] = __expf(m_r[i] - m_new);
            l_r[i] = l_r[i] * alpha_r[i] + ps;
            m_r[i] = m_new;
            #pragma unroll
            for (int j = 0; j < 4; ++j)
                Sp[row * 66 + cb * 4 + j] = (bf16_t)sc[i][j];
        }
        __syncthreads();

        // ---- O = O*alpha + P V ----
        #pragma unroll
        for (int i = 0; i < 4; ++i) {
            #pragma unroll
            for (int dj = 0; dj < 4; ++dj) o_reg[i][dj] *= alpha_r[i];
        }
        #pragma unroll 4
        for (int j = 0; j < 64; ++j) {
            float pj[4], vv[4];
            #pragma unroll
            for (int i = 0; i < 4; ++i) pj[i] = (float)Sp[(rb * 4 + i) * 66 + j];
            #pragma unroll
            for (int dj = 0; dj < 4; ++dj) vv[dj] = Vs[j * 65 + cb * 4 + dj];
            #pragma unroll
            for (int i = 0; i < 4; ++i)
                #pragma unroll
                for (int dj = 0; dj < 4; ++dj)
                    o_reg[i][dj] = fmaf(pj[i], vv[dj], o_reg[i][dj]);
        }
        __syncthreads();
    }

    const int b = bh >> 4, hh = bh & 15;
    #pragma unroll
    for (int i = 0; i < 4; ++i) {
        const int row = rb * 4 + i;
        const float inv_l = 1.0f / l_r[i];
        const size_t m = (size_t)b * 2048 + qt * 64 + row;
        #pragma unroll
        for (int dj = 0; dj < 4; ++dj)
            og[m * 1024 + hh * 64 + cb * 4 + dj] = (bf16_t)(o_reg[i][dj] * inv_l);
    }
}

// ---------------------------------------------------------------------------
// Kernel 3: d_out = og @ wo^T.  og bf16 [4096][1024], wo fp32 [1024][1024].
// d_out is FP32 (reference output dtype is float32).
// ---------------------------------------------------------------------------
__global__ __launch_bounds__(256) void out_gemm(
    const bf16_t* __restrict__ A,
    const float* __restrict__ W,
    float* __restrict__ C)
{
    __shared__ __align__(16) bf16_t As[128 * 32];
    __shared__ __align__(16) bf16_t Bs[128 * 32];

    const int tid = threadIdx.x;
    const int n0  = blockIdx.x * 128;
    const int m0  = blockIdx.y * 128;

    const int wave = tid >> 6;
    const int lane = tid & 63;
    const int wrow = (wave >> 1) * 64;
    const int wcol = (wave & 1) * 64;
    const int l16  = lane & 15;
    const int quad = lane >> 4;

    v4f acc[4][4];
    #pragma unroll
    for (int i = 0; i < 4; ++i)
        #pragma unroll
        for (int j = 0; j < 4; ++j) acc[i][j] = (v4f)(0.0f);

    for (int kt = 0; kt < 32; ++kt) {
        const int k0 = kt * 32;
        #pragma unroll
        for (int rep = 0; rep < 2; ++rep) {
            const int c   = rep * 256 + tid;
            const int row = c >> 2;
            const int col = (c & 3) * 8;
            // A: bf16 direct
            *(v8bf*)&As[c * 8] = *(const v8bf*)(A + (size_t)(m0 + row) * 1024 + k0 + col);
            // B: fp32 -> bf16
            const float* pb = W + (size_t)(n0 + row) * 1024 + k0 + col;
            const float4 b0 = *(const float4*)pb;
            const float4 b1 = *(const float4*)(pb + 4);
            v8bf bv;
            bv[0] = (bf16_t)b0.x; bv[1] = (bf16_t)b0.y; bv[2] = (bf16_t)b0.z; bv[3] = (bf16_t)b0.w;
            bv[4] = (bf16_t)b1.x; bv[5] = (bf16_t)b1.y; bv[6] = (bf16_t)b1.z; bv[7] = (bf16_t)b1.w;
            *(v8bf*)&Bs[c * 8] = bv;
        }
        __syncthreads();

        v8bf af[4], bfb[4];
        #pragma unroll
        for (int i = 0; i < 4; ++i) {
            af[i]  = *(const v8bf*)&As[(wrow + i * 16 + l16) * 32 + quad * 8];
            bfb[i] = *(const v8bf*)&Bs[(wcol + i * 16 + l16) * 32 + quad * 8];
        }
        #pragma unroll
        for (int i = 0; i < 4; ++i)
            #pragma unroll
            for (int j = 0; j < 4; ++j)
                acc[i][j] = __builtin_amdgcn_mfma_f32_16x16x32_bf16(
                    af[i], bfb[j], acc[i][j], 0, 0, 0);
        __syncthreads();
    }

    #pragma unroll
    for (int i = 0; i < 4; ++i)
        #pragma unroll
        for (int j = 0; j < 4; ++j)
            #pragma unroll
            for (int r = 0; r < 4; ++r) {
                const int m = m0 + wrow + i * 16 + quad * 4 + r;
                const int n = n0 + wcol + j * 16 + l16;
                C[(size_t)m * 1024 + n] = acc[i][j][r];   // fp32 store
            }
}

// ---------------------------------------------------------------------------
extern "C" void kernel_launch(void* const* d_in, const int* in_sizes, int n_in,
                              void* d_out, int out_size, void* d_ws, size_t ws_size,
                              hipStream_t stream) {
    const float* h  = (const float*)d_in[0];
    const float* wq = (const float*)d_in[1];
    const float* wk = (const float*)d_in[2];
    const float* wv = (const float*)d_in[3];
    const float* wo = (const float*)d_in[4];

    const size_t NH = (size_t)4096 * 1024;   // 4,194,304

    bf16_t* qw = (bf16_t*)d_ws;              // [32][2048][64]
    bf16_t* kw = qw + NH;
    bf16_t* vw = kw + NH;
    bf16_t* og = vw + NH;                    // [4096][1024]
    // total workspace: 32 MB

    qkv_gemm_rope<<<dim3(24, 32), dim3(256), 0, stream>>>(h, wq, wk, wv, qw, kw, vw);
    attn_kernel<<<dim3(32, 32), dim3(256), 0, stream>>>(qw, kw, vw, og);
    out_gemm<<<dim3(8, 32), dim3(256), 0, stream>>>(og, wo, (float*)d_out);
}

// Round 5
// 292.043 us; speedup vs baseline: 2.8400x; 2.8400x over previous
//
#include <hip/hip_runtime.h>
#include <math.h>

typedef __bf16 bf16_t;
typedef __bf16 v8bf __attribute__((ext_vector_type(8)));
typedef float  v4f  __attribute__((ext_vector_type(4)));

// ---------------------------------------------------------------------------
// Kernel 1: QKV = h @ [wq|wk|wv]^T with fused RoPE on Q,K.
// A (h) and W are fp32 in global; converted to bf16 during LDS staging.
// Output: Q,K as [B*H=32][T=2048][64] bf16;  V TRANSPOSED as [32][64][2048]
// (so attention's PV B-fragment read is a contiguous ds_read_b128).
// ---------------------------------------------------------------------------
__global__ __launch_bounds__(256) void qkv_gemm_rope(
    const float* __restrict__ A,    // h [4096][1024] fp32
    const float* __restrict__ wq,
    const float* __restrict__ wk,
    const float* __restrict__ wv,
    bf16_t* __restrict__ qo, bf16_t* __restrict__ ko, bf16_t* __restrict__ vo)
{
    __shared__ __align__(16) bf16_t As[128 * 32];
    __shared__ __align__(16) bf16_t Bs[128 * 32];

    const int tid = threadIdx.x;
    const int n0  = blockIdx.x * 128;       // 0..2944 (fused QKV columns)
    const int m0  = blockIdx.y * 128;
    const int sel = n0 >> 10;               // 0=Q 1=K 2=V
    const float* W = (sel == 0) ? wq : (sel == 1) ? wk : wv;
    const int wr0 = n0 & 1023;

    const int wave = tid >> 6;
    const int lane = tid & 63;
    const int wrow = (wave >> 1) * 64;
    const int wcol = (wave & 1) * 64;
    const int l16  = lane & 15;
    const int quad = lane >> 4;

    v4f acc[4][4];
    #pragma unroll
    for (int i = 0; i < 4; ++i)
        #pragma unroll
        for (int j = 0; j < 4; ++j) acc[i][j] = (v4f)(0.0f);

    for (int kt = 0; kt < 32; ++kt) {
        const int k0 = kt * 32;
        #pragma unroll
        for (int rep = 0; rep < 2; ++rep) {
            const int c   = rep * 256 + tid;     // chunk 0..511
            const int row = c >> 2;              // 0..127
            const int col = (c & 3) * 8;         // 0,8,16,24
            const float* pa = A + (size_t)(m0 + row) * 1024 + k0 + col;
            const float* pb = W + (size_t)(wr0 + row) * 1024 + k0 + col;
            const float4 a0 = *(const float4*)pa;
            const float4 a1 = *(const float4*)(pa + 4);
            const float4 b0 = *(const float4*)pb;
            const float4 b1 = *(const float4*)(pb + 4);
            v8bf av, bv;
            av[0] = (bf16_t)a0.x; av[1] = (bf16_t)a0.y; av[2] = (bf16_t)a0.z; av[3] = (bf16_t)a0.w;
            av[4] = (bf16_t)a1.x; av[5] = (bf16_t)a1.y; av[6] = (bf16_t)a1.z; av[7] = (bf16_t)a1.w;
            bv[0] = (bf16_t)b0.x; bv[1] = (bf16_t)b0.y; bv[2] = (bf16_t)b0.z; bv[3] = (bf16_t)b0.w;
            bv[4] = (bf16_t)b1.x; bv[5] = (bf16_t)b1.y; bv[6] = (bf16_t)b1.z; bv[7] = (bf16_t)b1.w;
            *(v8bf*)&As[c * 8] = av;
            *(v8bf*)&Bs[c * 8] = bv;
        }
        __syncthreads();

        v8bf af[4], bfb[4];
        #pragma unroll
        for (int i = 0; i < 4; ++i) {
            af[i]  = *(const v8bf*)&As[(wrow + i * 16 + l16) * 32 + quad * 8];
            bfb[i] = *(const v8bf*)&Bs[(wcol + i * 16 + l16) * 32 + quad * 8];
        }
        #pragma unroll
        for (int i = 0; i < 4; ++i)
            #pragma unroll
            for (int j = 0; j < 4; ++j)
                acc[i][j] = __builtin_amdgcn_mfma_f32_16x16x32_bf16(
                    af[i], bfb[j], acc[i][j], 0, 0, 0);
        __syncthreads();
    }

    bf16_t* OUT = (sel == 0) ? qo : (sel == 1) ? ko : vo;
    #pragma unroll
    for (int i = 0; i < 4; ++i) {
        #pragma unroll
        for (int j = 0; j < 4; ++j) {
            #pragma unroll
            for (int r = 0; r < 4; ++r) {
                const int row = wrow + i * 16 + quad * 4 + r;  // C/D: row=quad*4+reg
                const int col = wcol + j * 16 + l16;           //      col=lane&15
                const int m = m0 + row;
                const int n = n0 + col;
                float v = acc[i][j][r];
                const float vp = __shfl_xor(v, 1);  // RoPE partner: col n^1 = lane^1
                const int t = m & 2047;
                const int d = n & 63;
                if (sel < 2) {
                    const int kk = d >> 1;
                    const float freq = exp2f((float)kk * -0.4152410118609203f); // 10000^(-kk/32)
                    const float ang  = (float)t * freq;
                    float sn, cs;
                    sincosf(ang, &sn, &cs);
                    v = ((d & 1) == 0) ? (cs * v - sn * vp) : (sn * vp + cs * v);
                }
                const int b  = m >> 11;
                const int hd = (n >> 6) & 15;
                if (sel == 2)  // V transposed: [bh][d][t]
                    OUT[(((size_t)(b * 16 + hd) * 64) + d) * 2048 + t] = (bf16_t)v;
                else
                    OUT[(((size_t)(b * 16 + hd) * 2048) + t) * 64 + d] = (bf16_t)v;
            }
        }
    }
}

// ---------------------------------------------------------------------------
// Kernel 2: causal flash attention, MFMA (16x16x32 bf16).
// Q,K: [32][2048][64] bf16;  V^T: [32][64][2048] bf16.  og: [4096][1024] bf16.
// Block = 256 thr (4 waves). Block owns 64 Q rows (wave w -> rows w*16..+15,
// Q A-frags in registers, pre-scaled by 1/8). K-tiles of 64:
//   QK^T: 8 MFMA/wave; softmax in C-layout (row=quad*4+reg), col-reduce via
//   shfl_xor(1,2,4,8) inside each 16-lane quad group; P round-trips through
//   per-wave LDS (C-layout -> A-layout); PV: 8 MFMA/wave with V^T B-frags.
// LDS strides 72 elems (144 B): b128 reads/writes <=2-way bank aliased (free).
// ---------------------------------------------------------------------------
__global__ __launch_bounds__(256) void attn_mfma(
    const bf16_t* __restrict__ qg,
    const bf16_t* __restrict__ kg,
    const bf16_t* __restrict__ vtg,
    bf16_t* __restrict__ og)
{
    __shared__ __align__(16) bf16_t Ks[64 * 72];
    __shared__ __align__(16) bf16_t Vs[64 * 72];
    __shared__ __align__(16) bf16_t Ps[4][16 * 72];

    const int tid  = threadIdx.x;
    const int wave = tid >> 6;
    const int lane = tid & 63;
    const int l16  = lane & 15;
    const int quad = lane >> 4;
    const int qt   = 31 - blockIdx.x;   // reversed: long blocks dispatch first
    const int bh   = blockIdx.y;

    // Q A-fragments for this wave's 16 rows; fold in 1/sqrt(64)=0.125 (exact)
    const bf16_t* qrow = qg + (((size_t)bh * 2048) + (size_t)qt * 64 + wave * 16 + l16) * 64;
    v8bf qf[2];
    qf[0] = *(const v8bf*)(qrow + quad * 8);
    qf[1] = *(const v8bf*)(qrow + 32 + quad * 8);
    #pragma unroll
    for (int e = 0; e < 8; ++e) {
        qf[0][e] = (bf16_t)((float)qf[0][e] * 0.125f);
        qf[1][e] = (bf16_t)((float)qf[1][e] * 0.125f);
    }

    float m_r[4], l_r[4];
    v4f o_acc[4];
    #pragma unroll
    for (int r = 0; r < 4; ++r) { m_r[r] = -1e30f; l_r[r] = 0.0f; }
    #pragma unroll
    for (int dblk = 0; dblk < 4; ++dblk) o_acc[dblk] = (v4f)(0.0f);

    for (int kt = 0; kt <= qt; ++kt) {
        // ---- stage K tile [64 k][64 d] and V^T tile [64 d][64 k] ----
        #pragma unroll
        for (int rep = 0; rep < 2; ++rep) {
            const int c   = rep * 256 + tid;
            const int row = c >> 3;
            const int col = (c & 7) * 8;
            *(v8bf*)&Ks[row * 72 + col] =
                *(const v8bf*)(kg + (((size_t)bh * 2048) + (size_t)kt * 64 + row) * 64 + col);
            *(v8bf*)&Vs[row * 72 + col] =
                *(const v8bf*)(vtg + (((size_t)bh * 64) + row) * 2048 + (size_t)kt * 64 + col);
        }
        __syncthreads();

        // ---- S = (Q/8) K^T : 4 col-blocks x 2 K-dim MFMAs ----
        v4f s_acc[4];
        #pragma unroll
        for (int kblk = 0; kblk < 4; ++kblk) s_acc[kblk] = (v4f)(0.0f);
        #pragma unroll
        for (int kblk = 0; kblk < 4; ++kblk) {
            #pragma unroll
            for (int dblk = 0; dblk < 2; ++dblk) {
                const v8bf kf = *(const v8bf*)&Ks[(kblk * 16 + l16) * 72 + dblk * 32 + quad * 8];
                s_acc[kblk] = __builtin_amdgcn_mfma_f32_16x16x32_bf16(
                    qf[dblk], kf, s_acc[kblk], 0, 0, 0);
            }
        }

        // ---- causal mask (diagonal tile only) ----
        if (kt == qt) {
            #pragma unroll
            for (int kblk = 0; kblk < 4; ++kblk)
                #pragma unroll
                for (int r = 0; r < 4; ++r)
                    if (kblk * 16 + l16 > wave * 16 + quad * 4 + r)
                        s_acc[kblk][r] = -1e30f;
        }

        // ---- online softmax (per row; 16-lane quad group shares a row set) ----
        float alpha[4];
        #pragma unroll
        for (int r = 0; r < 4; ++r) {
            float mx = fmaxf(fmaxf(s_acc[0][r], s_acc[1][r]),
                             fmaxf(s_acc[2][r], s_acc[3][r]));
            #pragma unroll
            for (int msk = 1; msk < 16; msk <<= 1) mx = fmaxf(mx, __shfl_xor(mx, msk));
            const float m_new = fmaxf(m_r[r], mx);
            float s = 0.0f;
            #pragma unroll
            for (int kblk = 0; kblk < 4; ++kblk) {
                const float p = __expf(s_acc[kblk][r] - m_new);
                s_acc[kblk][r] = p;
                s += p;
            }
            #pragma unroll
            for (int msk = 1; msk < 16; msk <<= 1) s += __shfl_xor(s, msk);
            alpha[r] = __expf(m_r[r] - m_new);
            l_r[r] = l_r[r] * alpha[r] + s;
            m_r[r] = m_new;
        }

        // ---- P: C-layout -> per-wave LDS -> A-layout;  O *= alpha ----
        #pragma unroll
        for (int kblk = 0; kblk < 4; ++kblk)
            #pragma unroll
            for (int r = 0; r < 4; ++r)
                Ps[wave][(quad * 4 + r) * 72 + kblk * 16 + l16] = (bf16_t)s_acc[kblk][r];
        #pragma unroll
        for (int dblk = 0; dblk < 4; ++dblk)
            #pragma unroll
            for (int r = 0; r < 4; ++r)
                o_acc[dblk][r] *= alpha[r];

        // ---- O += P V : A-frag from own-wave LDS (in-order DS pipe) ----
        v8bf pf[2];
        pf[0] = *(const v8bf*)&Ps[wave][l16 * 72 + quad * 8];
        pf[1] = *(const v8bf*)&Ps[wave][l16 * 72 + 32 + quad * 8];
        #pragma unroll
        for (int dblk = 0; dblk < 4; ++dblk) {
            #pragma unroll
            for (int kk = 0; kk < 2; ++kk) {
                const v8bf vf = *(const v8bf*)&Vs[(dblk * 16 + l16) * 72 + kk * 32 + quad * 8];
                o_acc[dblk] = __builtin_amdgcn_mfma_f32_16x16x32_bf16(
                    pf[kk], vf, o_acc[dblk], 0, 0, 0);
            }
        }
        __syncthreads();
    }

    // ---- epilogue: normalize, store og[b][t][h*64+d] bf16 ----
    const int b = bh >> 4, hh = bh & 15;
    #pragma unroll
    for (int r = 0; r < 4; ++r) {
        const float inv_l = 1.0f / l_r[r];
        const size_t t    = (size_t)qt * 64 + wave * 16 + quad * 4 + r;
        const size_t base = ((size_t)b * 2048 + t) * 1024 + hh * 64;
        #pragma unroll
        for (int dblk = 0; dblk < 4; ++dblk)
            og[base + dblk * 16 + l16] = (bf16_t)(o_acc[dblk][r] * inv_l);
    }
}

// ---------------------------------------------------------------------------
// Kernel 3: d_out = og @ wo^T.  og bf16 [4096][1024], wo fp32 [1024][1024].
// d_out is FP32 (reference output dtype).
// ---------------------------------------------------------------------------
__global__ __launch_bounds__(256) void out_gemm(
    const bf16_t* __restrict__ A,
    const float* __restrict__ W,
    float* __restrict__ C)
{
    __shared__ __align__(16) bf16_t As[128 * 32];
    __shared__ __align__(16) bf16_t Bs[128 * 32];

    const int tid = threadIdx.x;
    const int n0  = blockIdx.x * 128;
    const int m0  = blockIdx.y * 128;

    const int wave = tid >> 6;
    const int lane = tid & 63;
    const int wrow = (wave >> 1) * 64;
    const int wcol = (wave & 1) * 64;
    const int l16  = lane & 15;
    const int quad = lane >> 4;

    v4f acc[4][4];
    #pragma unroll
    for (int i = 0; i < 4; ++i)
        #pragma unroll
        for (int j = 0; j < 4; ++j) acc[i][j] = (v4f)(0.0f);

    for (int kt = 0; kt < 32; ++kt) {
        const int k0 = kt * 32;
        #pragma unroll
        for (int rep = 0; rep < 2; ++rep) {
            const int c   = rep * 256 + tid;
            const int row = c >> 2;
            const int col = (c & 3) * 8;
            *(v8bf*)&As[c * 8] = *(const v8bf*)(A + (size_t)(m0 + row) * 1024 + k0 + col);
            const float* pb = W + (size_t)(n0 + row) * 1024 + k0 + col;
            const float4 b0 = *(const float4*)pb;
            const float4 b1 = *(const float4*)(pb + 4);
            v8bf bv;
            bv[0] = (bf16_t)b0.x; bv[1] = (bf16_t)b0.y; bv[2] = (bf16_t)b0.z; bv[3] = (bf16_t)b0.w;
            bv[4] = (bf16_t)b1.x; bv[5] = (bf16_t)b1.y; bv[6] = (bf16_t)b1.z; bv[7] = (bf16_t)b1.w;
            *(v8bf*)&Bs[c * 8] = bv;
        }
        __syncthreads();

        v8bf af[4], bfb[4];
        #pragma unroll
        for (int i = 0; i < 4; ++i) {
            af[i]  = *(const v8bf*)&As[(wrow + i * 16 + l16) * 32 + quad * 8];
            bfb[i] = *(const v8bf*)&Bs[(wcol + i * 16 + l16) * 32 + quad * 8];
        }
        #pragma unroll
        for (int i = 0; i < 4; ++i)
            #pragma unroll
            for (int j = 0; j < 4; ++j)
                acc[i][j] = __builtin_amdgcn_mfma_f32_16x16x32_bf16(
                    af[i], bfb[j], acc[i][j], 0, 0, 0);
        __syncthreads();
    }

    #pragma unroll
    for (int i = 0; i < 4; ++i)
        #pragma unroll
        for (int j = 0; j < 4; ++j)
            #pragma unroll
            for (int r = 0; r < 4; ++r) {
                const int m = m0 + wrow + i * 16 + quad * 4 + r;
                const int n = n0 + wcol + j * 16 + l16;
                C[(size_t)m * 1024 + n] = acc[i][j][r];   // fp32 store
            }
}

// ---------------------------------------------------------------------------
extern "C" void kernel_launch(void* const* d_in, const int* in_sizes, int n_in,
                              void* d_out, int out_size, void* d_ws, size_t ws_size,
                              hipStream_t stream) {
    const float* h  = (const float*)d_in[0];
    const float* wq = (const float*)d_in[1];
    const float* wk = (const float*)d_in[2];
    const float* wv = (const float*)d_in[3];
    const float* wo = (const float*)d_in[4];

    const size_t NH = (size_t)4096 * 1024;   // 4,194,304

    bf16_t* qw = (bf16_t*)d_ws;              // [32][2048][64]
    bf16_t* kw = qw + NH;                    // [32][2048][64]
    bf16_t* vw = kw + NH;                    // [32][64][2048]  (V transposed)
    bf16_t* og = vw + NH;                    // [4096][1024]
    // total workspace: 32 MB

    qkv_gemm_rope<<<dim3(24, 32), dim3(256), 0, stream>>>(h, wq, wk, wv, qw, kw, vw);
    attn_mfma<<<dim3(32, 32), dim3(256), 0, stream>>>(qw, kw, vw, og);
    out_gemm<<<dim3(8, 32), dim3(256), 0, stream>>>(og, wo, (float*)d_out);
}